// Round 1
// baseline (24425.038 us; speedup 1.0000x reference)
//
#include <hip/hip_runtime.h>

#define T_SEQ   32
#define N_NODES 10000
#define E_EDGES 160000
#define EF      (E_EDGES + N_NODES)
#define IN_CH   128
#define HID     64
#define HEADS   8
#define HC      512      // HEADS*HID
#define GRU_H   256
#define G3      768      // 3*GRU_H

__device__ __forceinline__ float wave_reduce_sum(float v){
#pragma unroll
  for (int off = 32; off; off >>= 1) v += __shfl_xor(v, off, 64);
  return v;
}

// ---------------- setup kernels ----------------

__global__ __launch_bounds__(256)
void deg_loop_kernel(const int* __restrict__ edst, const float* __restrict__ eattr,
                     int* __restrict__ deg, float* __restrict__ lsum){
  int e = blockIdx.x * 256 + threadIdx.x;
  if (e < E_EDGES){
    int d = edst[e];
    atomicAdd(&deg[d], 1);
    atomicAdd(&lsum[d*3+0], eattr[e*3+0]);
    atomicAdd(&lsum[d*3+1], eattr[e*3+1]);
    atomicAdd(&lsum[d*3+2], eattr[e*3+2]);
  }
}

__global__ __launch_bounds__(256)
void loop_div_kernel(const int* __restrict__ deg, const float* __restrict__ lsum,
                     float* __restrict__ lattr){
  int n = blockIdx.x * 256 + threadIdx.x;
  if (n < N_NODES){
    float d = fmaxf((float)deg[n], 1.0f);
    lattr[n*3+0] = lsum[n*3+0] / d;
    lattr[n*3+1] = lsum[n*3+1] / d;
    lattr[n*3+2] = lsum[n*3+2] / d;
  }
}

__global__ __launch_bounds__(256)
void scan_rowptr_kernel(const int* __restrict__ deg, int* __restrict__ row_ptr){
  __shared__ int sums[256];
  __shared__ int base[256];
  int tid = threadIdx.x;
  const int CH = 40;                 // 256*40 = 10240 >= 10001
  int start = tid * CH;
  int s = 0;
  for (int k = 0; k < CH; k++){
    int n = start + k;
    if (n < N_NODES) s += deg[n] + 1;   // +1 self loop
  }
  sums[tid] = s;
  __syncthreads();
  if (tid == 0){
    int acc = 0;
    for (int i = 0; i < 256; i++){ base[i] = acc; acc += sums[i]; }
  }
  __syncthreads();
  int acc = base[tid];
  for (int k = 0; k < CH; k++){
    int n = start + k;
    if (n < N_NODES){ row_ptr[n] = acc; acc += deg[n] + 1; }
    else if (n == N_NODES){ row_ptr[n] = acc; }
  }
}

__global__ __launch_bounds__(256)
void csr_fill_kernel(const int* __restrict__ edst, const int* __restrict__ row_ptr,
                     int* __restrict__ cursor, int* __restrict__ col){
  int e = blockIdx.x * 256 + threadIdx.x;
  if (e < EF){
    int d = (e < E_EDGES) ? edst[e] : (e - E_EDGES);
    int pos = row_ptr[d] + atomicAdd(&cursor[d], 1);
    col[pos] = e;
  }
}

__global__ __launch_bounds__(256)
void transpose_kernel(const float* __restrict__ W, float* __restrict__ WT, int R, int C){
  int idx = blockIdx.x * 256 + threadIdx.x;
  if (idx < R * C){
    int r = idx / C, c = idx - r * C;
    WT[(size_t)c * R + r] = W[idx];
  }
}

// ---------------- fp32 GEMM: C[M,N] = A[M,K] @ B[K,N]; N%64==0, K%16==0 -----
// 128x64 tile, 256 threads, each 8x4. grid.z==2 selects (A1,B1,C1).

__global__ __launch_bounds__(256)
void gemm_tile(const float* __restrict__ A0, const float* __restrict__ B0, float* __restrict__ C0,
               const float* __restrict__ A1, const float* __restrict__ B1, float* __restrict__ C1,
               int M, int N, int K){
  const float* A = blockIdx.z ? A1 : A0;
  const float* B = blockIdx.z ? B1 : B0;
  float*       C = blockIdx.z ? C1 : C0;
  __shared__ __align__(16) float As[16][132];   // [k][m], padded: 132*4B row stride, 16B-aligned
  __shared__ __align__(16) float Bs[16][64];    // [k][n]
  int tid = threadIdx.x;
  int m0 = blockIdx.x * 128;
  int n0 = blockIdx.y * 64;
  int tx = tid & 15;     // n block: tx*4
  int ty = tid >> 4;     // m block: ty*8
  float acc[8][4];
#pragma unroll
  for (int i = 0; i < 8; i++)
#pragma unroll
    for (int j = 0; j < 4; j++) acc[i][j] = 0.f;

  for (int k0 = 0; k0 < K; k0 += 16){
#pragma unroll
    for (int l = 0; l < 8; l++){
      int idx = l * 256 + tid;       // 0..2047
      int m = idx >> 4, kk = idx & 15;
      float v = 0.f;
      int gm = m0 + m;
      if (gm < M) v = A[(size_t)gm * K + k0 + kk];
      As[kk][m] = v;
    }
    {
      int kk = tid >> 4, n4 = (tid & 15) * 4;
      float4 bv = *reinterpret_cast<const float4*>(&B[(size_t)(k0 + kk) * N + n0 + n4]);
      *reinterpret_cast<float4*>(&Bs[kk][n4]) = bv;
    }
    __syncthreads();
#pragma unroll
    for (int kk = 0; kk < 16; kk++){
      float4 a0 = *reinterpret_cast<const float4*>(&As[kk][ty * 8]);
      float4 a1 = *reinterpret_cast<const float4*>(&As[kk][ty * 8 + 4]);
      float4 b  = *reinterpret_cast<const float4*>(&Bs[kk][tx * 4]);
      float am[8] = {a0.x, a0.y, a0.z, a0.w, a1.x, a1.y, a1.z, a1.w};
      float bn[4] = {b.x, b.y, b.z, b.w};
#pragma unroll
      for (int i = 0; i < 8; i++)
#pragma unroll
        for (int j = 0; j < 4; j++)
          acc[i][j] += am[i] * bn[j];
    }
    __syncthreads();
  }
#pragma unroll
  for (int i = 0; i < 8; i++){
    int gm = m0 + ty * 8 + i;
    if (gm < M){
      *reinterpret_cast<float4*>(&C[(size_t)gm * N + n0 + tx * 4]) =
        make_float4(acc[i][0], acc[i][1], acc[i][2], acc[i][3]);
    }
  }
}

// ---------------- GAT edge kernels ----------------
// one wave per edge; lane = channel

__global__ __launch_bounds__(256)
void gat1_logits_kernel(const float* __restrict__ xl, const float* __restrict__ xr,
                        const float* __restrict__ eattr, const float* __restrict__ lattr,
                        const int* __restrict__ esrc, const int* __restrict__ edst,
                        const float* __restrict__ we, const float* __restrict__ att,
                        float* __restrict__ logits){
  int wid = (blockIdx.x * 256 + threadIdx.x) >> 6;
  int lane = threadIdx.x & 63;
  if (wid >= EF) return;
  int s, d; float a0, a1, a2;
  if (wid < E_EDGES){
    s = esrc[wid]; d = edst[wid];
    a0 = eattr[wid*3]; a1 = eattr[wid*3+1]; a2 = eattr[wid*3+2];
  } else {
    s = d = wid - E_EDGES;
    a0 = lattr[s*3]; a1 = lattr[s*3+1]; a2 = lattr[s*3+2];
  }
  const float* xls = xl + (size_t)s * HC;
  const float* xrd = xr + (size_t)d * HC;
#pragma unroll
  for (int h = 0; h < HEADS; h++){
    int c = h * 64 + lane;
    float e = a0 * we[c] + a1 * we[HC + c] + a2 * we[2*HC + c];
    float v = xls[c] + xrd[c] + e;
    v = v > 0.f ? v : 0.2f * v;               // leaky_relu
    float t = wave_reduce_sum(v * att[c]);
    if (lane == 0) logits[(size_t)wid * HEADS + h] = t;
  }
}

__global__ __launch_bounds__(256)
void gat1_agg_kernel(const float* __restrict__ xl, const float* __restrict__ logits,
                     const int* __restrict__ row_ptr, const int* __restrict__ col,
                     const int* __restrict__ esrc, const float* __restrict__ bias,
                     float* __restrict__ out){
  int gw = (blockIdx.x * 256 + threadIdx.x) >> 6;  // (n,h)
  int lane = threadIdx.x & 63;
  if (gw >= N_NODES * HEADS) return;
  int n = gw >> 3, h = gw & 7;
  int beg = row_ptr[n], end = row_ptr[n+1];
  float mx = -1e30f;
  for (int p = beg; p < end; p++)
    mx = fmaxf(mx, logits[(size_t)col[p] * HEADS + h]);
  float den = 0.f, acc = 0.f;
  for (int p = beg; p < end; p++){
    int e = col[p];
    float w = __expf(logits[(size_t)e * HEADS + h] - mx);
    den += w;
    int s = (e < E_EDGES) ? esrc[e] : (e - E_EDGES);
    acc += w * xl[(size_t)s * HC + h * 64 + lane];
  }
  float o = acc / den + bias[h * 64 + lane];
  o = o > 0.f ? o : (__expf(o) - 1.f);        // ELU
  out[(size_t)n * HC + h * 64 + lane] = o;
}

__global__ __launch_bounds__(256)
void gat2_logits_kernel(const float* __restrict__ xl, const float* __restrict__ xr,
                        const float* __restrict__ eattr, const float* __restrict__ lattr,
                        const int* __restrict__ esrc, const int* __restrict__ edst,
                        const float* __restrict__ we, const float* __restrict__ att,
                        float* __restrict__ logits){
  int wid = (blockIdx.x * 256 + threadIdx.x) >> 6;
  int lane = threadIdx.x & 63;
  if (wid >= EF) return;
  int s, d; float a0, a1, a2;
  if (wid < E_EDGES){
    s = esrc[wid]; d = edst[wid];
    a0 = eattr[wid*3]; a1 = eattr[wid*3+1]; a2 = eattr[wid*3+2];
  } else {
    s = d = wid - E_EDGES;
    a0 = lattr[s*3]; a1 = lattr[s*3+1]; a2 = lattr[s*3+2];
  }
  float e = a0 * we[lane] + a1 * we[64 + lane] + a2 * we[128 + lane];
  float v = xl[(size_t)s * HID + lane] + xr[(size_t)d * HID + lane] + e;
  v = v > 0.f ? v : 0.2f * v;
  float t = wave_reduce_sum(v * att[lane]);
  if (lane == 0) logits[wid] = t;
}

__global__ __launch_bounds__(256)
void gat2_agg_kernel(const float* __restrict__ xl, const float* __restrict__ logits,
                     const int* __restrict__ row_ptr, const int* __restrict__ col,
                     const int* __restrict__ esrc, const float* __restrict__ bias,
                     float* __restrict__ out){
  int gw = (blockIdx.x * 256 + threadIdx.x) >> 6;  // node
  int lane = threadIdx.x & 63;
  if (gw >= N_NODES) return;
  int n = gw;
  int beg = row_ptr[n], end = row_ptr[n+1];
  float mx = -1e30f;
  for (int p = beg; p < end; p++) mx = fmaxf(mx, logits[col[p]]);
  float den = 0.f, acc = 0.f;
  for (int p = beg; p < end; p++){
    int e = col[p];
    float w = __expf(logits[e] - mx);
    den += w;
    int s = (e < E_EDGES) ? esrc[e] : (e - E_EDGES);
    acc += w * xl[(size_t)s * HID + lane];
  }
  float o = acc / den + bias[lane];
  o = o > 0.f ? o : (__expf(o) - 1.f);
  out[(size_t)n * HID + lane] = o;
}

// ---------------- GRU ----------------

__global__ __launch_bounds__(256)
void gru_cell_kernel(const float* __restrict__ gi, const float* __restrict__ gh,
                     const float* __restrict__ bih, const float* __restrict__ bhh,
                     float* __restrict__ h){
  int idx = blockIdx.x * 256 + threadIdx.x;
  if (idx >= N_NODES * GRU_H) return;
  int n = idx >> 8, j = idx & 255;
  const float* gin = gi + (size_t)n * G3;
  const float* ghn = gh + (size_t)n * G3;
  float ir  = gin[j]            + bih[j];
  float iz  = gin[GRU_H + j]    + bih[GRU_H + j];
  float in_ = gin[2*GRU_H + j]  + bih[2*GRU_H + j];
  float hr  = ghn[j]            + bhh[j];
  float hz  = ghn[GRU_H + j]    + bhh[GRU_H + j];
  float hn  = ghn[2*GRU_H + j]  + bhh[2*GRU_H + j];
  float r = 1.f / (1.f + __expf(-(ir + hr)));
  float z = 1.f / (1.f + __expf(-(iz + hz)));
  float nn = tanhf(in_ + r * hn);
  float hv = h[idx];
  h[idx] = (1.f - z) * nn + z * hv;
}

// ---------------- tail ----------------

__global__ __launch_bounds__(256)
void mean_kernel(const float* __restrict__ hf, const float* __restrict__ hb,
                 float* __restrict__ g){
  int k = threadIdx.x;                 // 0..255 = column
  int n0 = blockIdx.x * 50;
  int n1 = n0 + 50; if (n1 > N_NODES) n1 = N_NODES;
  float sf = 0.f, sb = 0.f;
  for (int n = n0; n < n1; n++){
    sf += hf[(size_t)n * GRU_H + k];
    sb += hb[(size_t)n * GRU_H + k];
  }
  atomicAdd(&g[k], sf);
  atomicAdd(&g[GRU_H + k], sb);
}

__global__ __launch_bounds__(64)
void fc_kernel(const float* __restrict__ g, const float* __restrict__ W,
               const float* __restrict__ b, float* __restrict__ out){
  int j = blockIdx.x;                  // 0..32
  int lane = threadIdx.x;              // 0..63
  float s = 0.f;
  for (int k = lane; k < 2 * GRU_H; k += 64) s += g[k] * W[j * (2 * GRU_H) + k];
  s = wave_reduce_sum(s);
  if (lane == 0) out[j] = b[j] + s * (1.0f / N_NODES);
}

// ---------------- launch ----------------

extern "C" void kernel_launch(void* const* d_in, const int* in_sizes, int n_in,
                              void* d_out, int out_size, void* d_ws, size_t ws_size,
                              hipStream_t stream){
  const float* x     = (const float*)d_in[0];
  const float* eattr = (const float*)d_in[1];
  const int*   esrc  = (const int*)  d_in[2];
  const int*   edst  = (const int*)  d_in[3];
  const float* g1_wl = (const float*)d_in[4];
  const float* g1_wr = (const float*)d_in[5];
  const float* g1_we = (const float*)d_in[6];
  const float* g1_att= (const float*)d_in[7];
  const float* g1_b  = (const float*)d_in[8];
  const float* g2_wl = (const float*)d_in[9];
  const float* g2_wr = (const float*)d_in[10];
  const float* g2_we = (const float*)d_in[11];
  const float* g2_att= (const float*)d_in[12];
  const float* g2_b  = (const float*)d_in[13];
  const float* wih_f = (const float*)d_in[14];
  const float* whh_f = (const float*)d_in[15];
  const float* bih_f = (const float*)d_in[16];
  const float* bhh_f = (const float*)d_in[17];
  const float* wih_b = (const float*)d_in[18];
  const float* whh_b = (const float*)d_in[19];
  const float* bih_b = (const float*)d_in[20];
  const float* bhh_b = (const float*)d_in[21];
  const float* fc_w  = (const float*)d_in[22];
  const float* fc_b  = (const float*)d_in[23];
  float* out = (float*)d_out;

  float* ws = (float*)d_ws;
  size_t o = 0;
  float* emb    = ws + o; o += (size_t)T_SEQ * N_NODES * HID;   // 20,480,000
  float* hf     = ws + o; o += (size_t)N_NODES * GRU_H;         //  2,560,000
  float* hb     = ws + o; o += (size_t)N_NODES * GRU_H;
  float* wihT_f = ws + o; o += (size_t)HID * G3;
  float* whhT_f = ws + o; o += (size_t)GRU_H * G3;
  float* wihT_b = ws + o; o += (size_t)HID * G3;
  float* whhT_b = ws + o; o += (size_t)GRU_H * G3;
  float* lsum   = ws + o; o += (size_t)N_NODES * 3;
  float* lattr  = ws + o; o += (size_t)N_NODES * 3;
  float* gmean  = ws + o; o += 512;
  float* shared = ws + o;
  // GAT view of shared region (18,170,000 floats)
  float* xl1     = shared;
  float* xr1     = xl1 + (size_t)N_NODES * HC;
  float* h1      = xr1 + (size_t)N_NODES * HC;
  float* xl2     = h1  + (size_t)N_NODES * HC;
  float* xr2     = xl2 + (size_t)N_NODES * HID;
  float* logits1 = xr2 + (size_t)N_NODES * HID;
  float* logits2 = logits1 + (size_t)EF * HEADS;
  // GRU view of the same region (15,360,000 floats)
  float* gi = shared;
  float* gh = gi + (size_t)N_NODES * G3;
  o += 18170000;
  int* deg     = (int*)(ws + o);
  int* row_ptr = deg + N_NODES;
  int* cursor  = row_ptr + N_NODES + 1;
  int* col     = cursor + N_NODES;

  hipMemsetAsync(deg,    0, N_NODES * sizeof(int), stream);
  hipMemsetAsync(cursor, 0, N_NODES * sizeof(int), stream);
  hipMemsetAsync(lsum,   0, (size_t)N_NODES * 3 * sizeof(float), stream);
  hipMemsetAsync(hf,     0, (size_t)N_NODES * GRU_H * sizeof(float), stream);
  hipMemsetAsync(hb,     0, (size_t)N_NODES * GRU_H * sizeof(float), stream);
  hipMemsetAsync(gmean,  0, 512 * sizeof(float), stream);

  deg_loop_kernel<<<(E_EDGES + 255) / 256, 256, 0, stream>>>(edst, eattr, deg, lsum);
  loop_div_kernel<<<(N_NODES + 255) / 256, 256, 0, stream>>>(deg, lsum, lattr);
  scan_rowptr_kernel<<<1, 256, 0, stream>>>(deg, row_ptr);
  csr_fill_kernel<<<(EF + 255) / 256, 256, 0, stream>>>(edst, row_ptr, cursor, col);
  transpose_kernel<<<(G3 * HID   + 255) / 256, 256, 0, stream>>>(wih_f, wihT_f, G3, HID);
  transpose_kernel<<<(G3 * GRU_H + 255) / 256, 256, 0, stream>>>(whh_f, whhT_f, G3, GRU_H);
  transpose_kernel<<<(G3 * HID   + 255) / 256, 256, 0, stream>>>(wih_b, wihT_b, G3, HID);
  transpose_kernel<<<(G3 * GRU_H + 255) / 256, 256, 0, stream>>>(whh_b, whhT_b, G3, GRU_H);

  const int MT = (N_NODES + 127) / 128;     // 79
  for (int t = 0; t < T_SEQ; t++){
    const float* xt = x + (size_t)t * N_NODES * IN_CH;
    gemm_tile<<<dim3(MT, HC / 64, 2), 256, 0, stream>>>(
        xt, g1_wl, xl1, xt, g1_wr, xr1, N_NODES, HC, IN_CH);
    gat1_logits_kernel<<<(EF + 3) / 4, 256, 0, stream>>>(
        xl1, xr1, eattr, lattr, esrc, edst, g1_we, g1_att, logits1);
    gat1_agg_kernel<<<(N_NODES * HEADS + 3) / 4, 256, 0, stream>>>(
        xl1, logits1, row_ptr, col, esrc, g1_b, h1);
    gemm_tile<<<dim3(MT, 1, 2), 256, 0, stream>>>(
        h1, g2_wl, xl2, h1, g2_wr, xr2, N_NODES, HID, HC);
    gat2_logits_kernel<<<(EF + 3) / 4, 256, 0, stream>>>(
        xl2, xr2, eattr, lattr, esrc, edst, g2_we, g2_att, logits2);
    gat2_agg_kernel<<<(N_NODES + 3) / 4, 256, 0, stream>>>(
        xl2, logits2, row_ptr, col, esrc, g2_b, emb + (size_t)t * N_NODES * HID);
  }

  for (int dir = 0; dir < 2; dir++){
    const float* wihT = dir ? wihT_b : wihT_f;
    const float* whhT = dir ? whhT_b : whhT_f;
    const float* bih  = dir ? bih_b  : bih_f;
    const float* bhh  = dir ? bhh_b  : bhh_f;
    float* h = dir ? hb : hf;
    for (int s = 0; s < T_SEQ; s++){
      int t = dir ? (T_SEQ - 1 - s) : s;
      gemm_tile<<<dim3(MT, G3 / 64, 1), 256, 0, stream>>>(
          emb + (size_t)t * N_NODES * HID, wihT, gi,
          nullptr, nullptr, nullptr, N_NODES, G3, HID);
      gemm_tile<<<dim3(MT, G3 / 64, 1), 256, 0, stream>>>(
          h, whhT, gh, nullptr, nullptr, nullptr, N_NODES, G3, GRU_H);
      gru_cell_kernel<<<(N_NODES * GRU_H + 255) / 256, 256, 0, stream>>>(
          gi, gh, bih, bhh, h);
    }
  }

  mean_kernel<<<(N_NODES + 49) / 50, 256, 0, stream>>>(hf, hb, gmean);
  fc_kernel<<<33, 64, 0, stream>>>(gmean, fc_w, fc_b, out);
}

// Round 2
// 11908.138 us; speedup vs baseline: 2.0511x; 2.0511x over previous
//
#include <hip/hip_runtime.h>

#define T_SEQ   32
#define N_NODES 10000
#define E_EDGES 160000
#define EF      (E_EDGES + N_NODES)
#define IN_CH   128
#define HID     64
#define HEADS   8
#define HC      512
#define GRU_H   256
#define G3      768

typedef __attribute__((ext_vector_type(8))) short short8;
typedef __attribute__((ext_vector_type(4))) float f32x4;

__device__ __forceinline__ float wave_reduce_sum(float v){
#pragma unroll
  for (int off = 32; off; off >>= 1) v += __shfl_xor(v, off, 64);
  return v;
}

__device__ __forceinline__ unsigned short f2bf(float v){
  unsigned u = __float_as_uint(v);
  unsigned r = u + 0x7FFFu + ((u >> 16) & 1u);
  return (unsigned short)(r >> 16);
}
__device__ __forceinline__ float bf2f(unsigned short b){
  return __uint_as_float(((unsigned)b) << 16);
}

// ---------------- graph setup ----------------

__global__ __launch_bounds__(256)
void deg_loop_kernel(const int* __restrict__ edst, const float* __restrict__ eattr,
                     int* __restrict__ deg, float* __restrict__ lsum){
  int e = blockIdx.x * 256 + threadIdx.x;
  if (e < E_EDGES){
    int d = edst[e];
    atomicAdd(&deg[d], 1);
    atomicAdd(&lsum[d*3+0], eattr[e*3+0]);
    atomicAdd(&lsum[d*3+1], eattr[e*3+1]);
    atomicAdd(&lsum[d*3+2], eattr[e*3+2]);
  }
}

__global__ __launch_bounds__(256)
void loop_div_kernel(const int* __restrict__ deg, const float* __restrict__ lsum,
                     float* __restrict__ lattr){
  int n = blockIdx.x * 256 + threadIdx.x;
  if (n < N_NODES){
    float d = fmaxf((float)deg[n], 1.0f);
    lattr[n*3+0] = lsum[n*3+0] / d;
    lattr[n*3+1] = lsum[n*3+1] / d;
    lattr[n*3+2] = lsum[n*3+2] / d;
  }
}

__global__ __launch_bounds__(256)
void scan_rowptr_kernel(const int* __restrict__ deg, int* __restrict__ row_ptr){
  __shared__ int sums[256];
  __shared__ int base[256];
  int tid = threadIdx.x;
  const int CH = 40;
  int start = tid * CH;
  int s = 0;
  for (int k = 0; k < CH; k++){
    int n = start + k;
    if (n < N_NODES) s += deg[n] + 1;
  }
  sums[tid] = s;
  __syncthreads();
  if (tid == 0){
    int acc = 0;
    for (int i = 0; i < 256; i++){ base[i] = acc; acc += sums[i]; }
  }
  __syncthreads();
  int acc = base[tid];
  for (int k = 0; k < CH; k++){
    int n = start + k;
    if (n < N_NODES){ row_ptr[n] = acc; acc += deg[n] + 1; }
    else if (n == N_NODES){ row_ptr[n] = acc; }
  }
}

__global__ __launch_bounds__(256)
void csr_fill_kernel(const int* __restrict__ edst, const int* __restrict__ row_ptr,
                     int* __restrict__ cursor, int* __restrict__ col){
  int e = blockIdx.x * 256 + threadIdx.x;
  if (e < EF){
    int d = (e < E_EDGES) ? edst[e] : (e - E_EDGES);
    int pos = row_ptr[d] + atomicAdd(&cursor[d], 1);
    col[pos] = e;
  }
}

// ---------------- weight prep: transpose + hi/lo bf16 split ----------------
// GAT1: B = [wl | wr] : [128][1024] -> W1T[n][k], n<1024, k<128
__global__ __launch_bounds__(256)
void split_w_gat1(const float* __restrict__ wl, const float* __restrict__ wr,
                  unsigned short* __restrict__ hi, unsigned short* __restrict__ lo){
  int idx = blockIdx.x * 256 + threadIdx.x;
  if (idx >= 1024 * 128) return;
  int n = idx >> 7, k = idx & 127;
  float v = (n < 512) ? wl[k * 512 + n] : wr[k * 512 + (n - 512)];
  unsigned short h = f2bf(v);
  hi[idx] = h; lo[idx] = f2bf(v - bf2f(h));
}

// GAT2: B = [wl2 | wr2] : [512][128] -> W2T[n][k], n<128, k<512
__global__ __launch_bounds__(256)
void split_w_gat2(const float* __restrict__ wl, const float* __restrict__ wr,
                  unsigned short* __restrict__ hi, unsigned short* __restrict__ lo){
  int idx = blockIdx.x * 256 + threadIdx.x;
  if (idx >= 128 * 512) return;
  int n = idx >> 9, k = idx & 511;
  float v = (n < 64) ? wl[k * 64 + n] : wr[k * 64 + (n - 64)];
  unsigned short h = f2bf(v);
  hi[idx] = h; lo[idx] = f2bf(v - bf2f(h));
}

// GRU: Wg[n][k] = k<64 ? wih[n][k] : whh[n][k-64]; [768][320]
__global__ __launch_bounds__(256)
void split_w_gru(const float* __restrict__ wih, const float* __restrict__ whh,
                 unsigned short* __restrict__ hi, unsigned short* __restrict__ lo){
  int idx = blockIdx.x * 256 + threadIdx.x;
  if (idx >= G3 * 320) return;
  int n = idx / 320, k = idx - n * 320;
  float v = (k < 64) ? wih[n * 64 + k] : whh[n * 256 + (k - 64)];
  unsigned short h = f2bf(v);
  hi[idx] = h; lo[idx] = f2bf(v - bf2f(h));
}

// ---------------- bf16x3 MFMA GEMM: C[M,N] = A[M,K] @ B^T  ----------------
// A fp32 [M][K]; B pre-split bf16 [N][K]; C fp32 [M][N].
// BM=64, BN=64, BK=32; 256 threads = 4 waves in 2x2; wave = 32 rows x 32 cols.
#define LDK 40   // padded LDS row (shorts)

__global__ __launch_bounds__(256)
void mgemm(const float* __restrict__ A, const unsigned short* __restrict__ Bh,
           const unsigned short* __restrict__ Bl, float* __restrict__ C,
           int M, int K, int N){
  __shared__ __align__(16) short As_h[64 * LDK];
  __shared__ __align__(16) short As_l[64 * LDK];
  __shared__ __align__(16) short Bs_h[64 * LDK];
  __shared__ __align__(16) short Bs_l[64 * LDK];
  int tid = threadIdx.x;
  int m0 = blockIdx.x * 64, n0 = blockIdx.y * 64;
  int w = tid >> 6, lane = tid & 63;
  int wm = w >> 1, wn = w & 1;
  int m16 = lane & 15, quad = lane >> 4;

  f32x4 acc[2][2];
#pragma unroll
  for (int i = 0; i < 2; i++)
#pragma unroll
    for (int j = 0; j < 2; j++) acc[i][j] = (f32x4){0.f,0.f,0.f,0.f};

  int ar = tid >> 2;              // 0..63
  int ak = (tid & 3) * 8;         // 0,8,16,24
  bool aval = (m0 + ar) < M;
  const float* Ap = A + (size_t)(m0 + ar) * K + ak;
  int bn = tid >> 2;
  int bk = (tid & 3) * 8;
  const unsigned short* Bhp = Bh + (size_t)(n0 + bn) * K + bk;
  const unsigned short* Blp = Bl + (size_t)(n0 + bn) * K + bk;

  for (int k0 = 0; k0 < K; k0 += 32){
#pragma unroll
    for (int c = 0; c < 2; c++){
      float4 v = aval ? *(const float4*)(Ap + k0 + c * 4) : make_float4(0,0,0,0);
      unsigned short h0=f2bf(v.x), h1=f2bf(v.y), h2=f2bf(v.z), h3=f2bf(v.w);
      unsigned short l0=f2bf(v.x-bf2f(h0)), l1=f2bf(v.y-bf2f(h1)),
                     l2=f2bf(v.z-bf2f(h2)), l3=f2bf(v.w-bf2f(h3));
      *(ushort4*)&As_h[ar*LDK + ak + c*4] = make_ushort4(h0,h1,h2,h3);
      *(ushort4*)&As_l[ar*LDK + ak + c*4] = make_ushort4(l0,l1,l2,l3);
    }
    *(float4*)&Bs_h[bn*LDK + bk] = *(const float4*)(Bhp + k0);
    *(float4*)&Bs_l[bn*LDK + bk] = *(const float4*)(Blp + k0);
    __syncthreads();

    short8 a_h[2], a_l[2], b_h[2], b_l[2];
#pragma unroll
    for (int mt = 0; mt < 2; mt++){
      int r = wm*32 + mt*16 + m16;
      a_h[mt] = *(const short8*)&As_h[r*LDK + quad*8];
      a_l[mt] = *(const short8*)&As_l[r*LDK + quad*8];
    }
#pragma unroll
    for (int nt = 0; nt < 2; nt++){
      int r = wn*32 + nt*16 + m16;
      b_h[nt] = *(const short8*)&Bs_h[r*LDK + quad*8];
      b_l[nt] = *(const short8*)&Bs_l[r*LDK + quad*8];
    }
#pragma unroll
    for (int mt = 0; mt < 2; mt++)
#pragma unroll
      for (int nt = 0; nt < 2; nt++){
        acc[mt][nt] = __builtin_amdgcn_mfma_f32_16x16x32_bf16(a_h[mt], b_h[nt], acc[mt][nt], 0,0,0);
        acc[mt][nt] = __builtin_amdgcn_mfma_f32_16x16x32_bf16(a_h[mt], b_l[nt], acc[mt][nt], 0,0,0);
        acc[mt][nt] = __builtin_amdgcn_mfma_f32_16x16x32_bf16(a_l[mt], b_h[nt], acc[mt][nt], 0,0,0);
      }
    __syncthreads();
  }
#pragma unroll
  for (int mt = 0; mt < 2; mt++){
    int row = m0 + wm*32 + mt*16 + quad*4;
#pragma unroll
    for (int nt = 0; nt < 2; nt++){
      int cc = n0 + wn*32 + nt*16 + m16;
#pragma unroll
      for (int r4 = 0; r4 < 4; r4++){
        if (row + r4 < M) C[(size_t)(row + r4) * N + cc] = acc[mt][nt][r4];
      }
    }
  }
}

// ---------------- fused GRU step: h' = cell([emb_t|h] @ Wg^T) -------------
// Wg [768][320] pre-split. Block: 64 rows x (64 cols per gate x 3 gates).
__global__ __launch_bounds__(256)
void gru_step(const float* __restrict__ Et, const float* __restrict__ Hin,
              const unsigned short* __restrict__ Wh, const unsigned short* __restrict__ Wl,
              const float* __restrict__ bih, const float* __restrict__ bhh,
              float* __restrict__ Hout){
  __shared__ __align__(16) short As_h[64 * LDK];
  __shared__ __align__(16) short As_l[64 * LDK];
  __shared__ __align__(16) short Bs_h[3 * 64 * LDK];
  __shared__ __align__(16) short Bs_l[3 * 64 * LDK];
  int tid = threadIdx.x;
  int m0 = blockIdx.x * 64;
  int j0 = blockIdx.y * 64;
  int w = tid >> 6, lane = tid & 63;
  int wm = w >> 1, wn = w & 1;
  int m16 = lane & 15, quad = lane >> 4;

  f32x4 acc_r[2][2], acc_z[2][2], acc_ni[2][2], acc_nh[2][2];
#pragma unroll
  for (int i = 0; i < 2; i++)
#pragma unroll
    for (int j = 0; j < 2; j++){
      acc_r[i][j] = (f32x4){0,0,0,0}; acc_z[i][j] = (f32x4){0,0,0,0};
      acc_ni[i][j] = (f32x4){0,0,0,0}; acc_nh[i][j] = (f32x4){0,0,0,0};
    }

  int ar = tid >> 2;
  int ak = (tid & 3) * 8;
  bool aval = (m0 + ar) < N_NODES;
  int bn = tid >> 2;
  int bk = (tid & 3) * 8;

  for (int k0 = 0; k0 < 320; k0 += 32){
    const float* src; int stride, koff;
    if (k0 < 64){ src = Et; stride = 64; koff = k0; }
    else        { src = Hin; stride = GRU_H; koff = k0 - 64; }
#pragma unroll
    for (int c = 0; c < 2; c++){
      float4 v = aval ? *(const float4*)(src + (size_t)(m0 + ar) * stride + koff + ak + c * 4)
                      : make_float4(0,0,0,0);
      unsigned short h0=f2bf(v.x), h1=f2bf(v.y), h2=f2bf(v.z), h3=f2bf(v.w);
      unsigned short l0=f2bf(v.x-bf2f(h0)), l1=f2bf(v.y-bf2f(h1)),
                     l2=f2bf(v.z-bf2f(h2)), l3=f2bf(v.w-bf2f(h3));
      *(ushort4*)&As_h[ar*LDK + ak + c*4] = make_ushort4(h0,h1,h2,h3);
      *(ushort4*)&As_l[ar*LDK + ak + c*4] = make_ushort4(l0,l1,l2,l3);
    }
#pragma unroll
    for (int g = 0; g < 3; g++){
      size_t wrow = (size_t)(g * GRU_H + j0 + bn) * 320 + k0 + bk;
      *(float4*)&Bs_h[(g*64 + bn)*LDK + bk] = *(const float4*)(Wh + wrow);
      *(float4*)&Bs_l[(g*64 + bn)*LDK + bk] = *(const float4*)(Wl + wrow);
    }
    __syncthreads();

    short8 a_h[2], a_l[2];
#pragma unroll
    for (int mt = 0; mt < 2; mt++){
      int r = wm*32 + mt*16 + m16;
      a_h[mt] = *(const short8*)&As_h[r*LDK + quad*8];
      a_l[mt] = *(const short8*)&As_l[r*LDK + quad*8];
    }
#pragma unroll
    for (int g = 0; g < 3; g++){
      short8 b_h[2], b_l[2];
#pragma unroll
      for (int nt = 0; nt < 2; nt++){
        int r = g*64 + wn*32 + nt*16 + m16;
        b_h[nt] = *(const short8*)&Bs_h[r*LDK + quad*8];
        b_l[nt] = *(const short8*)&Bs_l[r*LDK + quad*8];
      }
      if (g == 0){
#pragma unroll
        for (int mt = 0; mt < 2; mt++)
#pragma unroll
          for (int nt = 0; nt < 2; nt++){
            acc_r[mt][nt] = __builtin_amdgcn_mfma_f32_16x16x32_bf16(a_h[mt], b_h[nt], acc_r[mt][nt],0,0,0);
            acc_r[mt][nt] = __builtin_amdgcn_mfma_f32_16x16x32_bf16(a_h[mt], b_l[nt], acc_r[mt][nt],0,0,0);
            acc_r[mt][nt] = __builtin_amdgcn_mfma_f32_16x16x32_bf16(a_l[mt], b_h[nt], acc_r[mt][nt],0,0,0);
          }
      } else if (g == 1){
#pragma unroll
        for (int mt = 0; mt < 2; mt++)
#pragma unroll
          for (int nt = 0; nt < 2; nt++){
            acc_z[mt][nt] = __builtin_amdgcn_mfma_f32_16x16x32_bf16(a_h[mt], b_h[nt], acc_z[mt][nt],0,0,0);
            acc_z[mt][nt] = __builtin_amdgcn_mfma_f32_16x16x32_bf16(a_h[mt], b_l[nt], acc_z[mt][nt],0,0,0);
            acc_z[mt][nt] = __builtin_amdgcn_mfma_f32_16x16x32_bf16(a_l[mt], b_h[nt], acc_z[mt][nt],0,0,0);
          }
      } else if (k0 < 64){
#pragma unroll
        for (int mt = 0; mt < 2; mt++)
#pragma unroll
          for (int nt = 0; nt < 2; nt++){
            acc_ni[mt][nt] = __builtin_amdgcn_mfma_f32_16x16x32_bf16(a_h[mt], b_h[nt], acc_ni[mt][nt],0,0,0);
            acc_ni[mt][nt] = __builtin_amdgcn_mfma_f32_16x16x32_bf16(a_h[mt], b_l[nt], acc_ni[mt][nt],0,0,0);
            acc_ni[mt][nt] = __builtin_amdgcn_mfma_f32_16x16x32_bf16(a_l[mt], b_h[nt], acc_ni[mt][nt],0,0,0);
          }
      } else {
#pragma unroll
        for (int mt = 0; mt < 2; mt++)
#pragma unroll
          for (int nt = 0; nt < 2; nt++){
            acc_nh[mt][nt] = __builtin_amdgcn_mfma_f32_16x16x32_bf16(a_h[mt], b_h[nt], acc_nh[mt][nt],0,0,0);
            acc_nh[mt][nt] = __builtin_amdgcn_mfma_f32_16x16x32_bf16(a_h[mt], b_l[nt], acc_nh[mt][nt],0,0,0);
            acc_nh[mt][nt] = __builtin_amdgcn_mfma_f32_16x16x32_bf16(a_l[mt], b_h[nt], acc_nh[mt][nt],0,0,0);
          }
      }
    }
    __syncthreads();
  }

#pragma unroll
  for (int mt = 0; mt < 2; mt++){
    int row = m0 + wm*32 + mt*16 + quad*4;
#pragma unroll
    for (int nt = 0; nt < 2; nt++){
      int j = j0 + wn*32 + nt*16 + m16;
      float br = bih[j] + bhh[j];
      float bz = bih[GRU_H + j] + bhh[GRU_H + j];
      float bni = bih[2*GRU_H + j];
      float bnh = bhh[2*GRU_H + j];
#pragma unroll
      for (int r4 = 0; r4 < 4; r4++){
        int node = row + r4;
        if (node < N_NODES){
          float r = 1.f / (1.f + __expf(-(acc_r[mt][nt][r4] + br)));
          float z = 1.f / (1.f + __expf(-(acc_z[mt][nt][r4] + bz)));
          float nn = tanhf(acc_ni[mt][nt][r4] + bni + r * (acc_nh[mt][nt][r4] + bnh));
          float hold = Hin[(size_t)node * GRU_H + j];
          Hout[(size_t)node * GRU_H + j] = (1.f - z) * nn + z * hold;
        }
      }
    }
  }
}

// ---------------- fused GAT (online softmax) ----------------

__global__ __launch_bounds__(256)
void gat1_fused(const float* __restrict__ xlr, const float* __restrict__ eattr,
                const float* __restrict__ lattr, const int* __restrict__ esrc,
                const int* __restrict__ row_ptr, const int* __restrict__ col,
                const float* __restrict__ we, const float* __restrict__ att,
                const float* __restrict__ bias, float* __restrict__ out){
  int gw = (blockIdx.x * 256 + threadIdx.x) >> 6;
  int lane = threadIdx.x & 63;
  if (gw >= N_NODES * HEADS) return;
  int n = gw >> 3, h = gw & 7;
  int c = h * 64 + lane;
  float xr_c = xlr[(size_t)n * 1024 + 512 + c];
  float att_c = att[c];
  float we0 = we[c], we1 = we[HC + c], we2 = we[2*HC + c];
  int beg = row_ptr[n], end = row_ptr[n + 1];
  float m = -1e30f, den = 0.f, acc = 0.f;
  for (int p = beg; p < end; p++){
    int e = col[p];
    int s; float a0, a1, a2;
    if (e < E_EDGES){ s = esrc[e]; a0 = eattr[e*3]; a1 = eattr[e*3+1]; a2 = eattr[e*3+2]; }
    else { s = e - E_EDGES; a0 = lattr[s*3]; a1 = lattr[s*3+1]; a2 = lattr[s*3+2]; }
    float xl_c = xlr[(size_t)s * 1024 + c];
    float v = xl_c + xr_c + a0*we0 + a1*we1 + a2*we2;
    v = v > 0.f ? v : 0.2f * v;
    float lg = wave_reduce_sum(v * att_c);
    float nm = fmaxf(m, lg);
    float sc = __expf(m - nm);
    float wt = __expf(lg - nm);
    den = den * sc + wt;
    acc = acc * sc + wt * xl_c;
    m = nm;
  }
  float o = acc / den + bias[c];
  out[(size_t)n * HC + c] = o > 0.f ? o : (__expf(o) - 1.f);
}

__global__ __launch_bounds__(256)
void gat2_fused(const float* __restrict__ xlr, const float* __restrict__ eattr,
                const float* __restrict__ lattr, const int* __restrict__ esrc,
                const int* __restrict__ row_ptr, const int* __restrict__ col,
                const float* __restrict__ we, const float* __restrict__ att,
                const float* __restrict__ bias, float* __restrict__ out){
  int gw = (blockIdx.x * 256 + threadIdx.x) >> 6;
  int lane = threadIdx.x & 63;
  if (gw >= N_NODES) return;
  int n = gw;
  float xr_c = xlr[(size_t)n * 128 + 64 + lane];
  float att_c = att[lane];
  float we0 = we[lane], we1 = we[64 + lane], we2 = we[128 + lane];
  int beg = row_ptr[n], end = row_ptr[n + 1];
  float m = -1e30f, den = 0.f, acc = 0.f;
  for (int p = beg; p < end; p++){
    int e = col[p];
    int s; float a0, a1, a2;
    if (e < E_EDGES){ s = esrc[e]; a0 = eattr[e*3]; a1 = eattr[e*3+1]; a2 = eattr[e*3+2]; }
    else { s = e - E_EDGES; a0 = lattr[s*3]; a1 = lattr[s*3+1]; a2 = lattr[s*3+2]; }
    float xl_c = xlr[(size_t)s * 128 + lane];
    float v = xl_c + xr_c + a0*we0 + a1*we1 + a2*we2;
    v = v > 0.f ? v : 0.2f * v;
    float lg = wave_reduce_sum(v * att_c);
    float nm = fmaxf(m, lg);
    float sc = __expf(m - nm);
    float wt = __expf(lg - nm);
    den = den * sc + wt;
    acc = acc * sc + wt * xl_c;
    m = nm;
  }
  float o = acc / den + bias[lane];
  out[(size_t)n * HID + lane] = o > 0.f ? o : (__expf(o) - 1.f);
}

// ---------------- tail ----------------

__global__ __launch_bounds__(256)
void mean_kernel(const float* __restrict__ hf, const float* __restrict__ hb,
                 float* __restrict__ g){
  int k = threadIdx.x;
  int n0 = blockIdx.x * 50;
  int n1 = n0 + 50; if (n1 > N_NODES) n1 = N_NODES;
  float sf = 0.f, sb = 0.f;
  for (int n = n0; n < n1; n++){
    sf += hf[(size_t)n * GRU_H + k];
    sb += hb[(size_t)n * GRU_H + k];
  }
  atomicAdd(&g[k], sf);
  atomicAdd(&g[GRU_H + k], sb);
}

__global__ __launch_bounds__(64)
void fc_kernel(const float* __restrict__ g, const float* __restrict__ W,
               const float* __restrict__ b, float* __restrict__ out){
  int j = blockIdx.x;
  int lane = threadIdx.x;
  float s = 0.f;
  for (int k = lane; k < 2 * GRU_H; k += 64) s += g[k] * W[j * (2 * GRU_H) + k];
  s = wave_reduce_sum(s);
  if (lane == 0) out[j] = b[j] + s * (1.0f / N_NODES);
}

// ---------------- launch ----------------

extern "C" void kernel_launch(void* const* d_in, const int* in_sizes, int n_in,
                              void* d_out, int out_size, void* d_ws, size_t ws_size,
                              hipStream_t stream){
  const float* x     = (const float*)d_in[0];
  const float* eattr = (const float*)d_in[1];
  const int*   esrc  = (const int*)  d_in[2];
  const int*   edst  = (const int*)  d_in[3];
  const float* g1_wl = (const float*)d_in[4];
  const float* g1_wr = (const float*)d_in[5];
  const float* g1_we = (const float*)d_in[6];
  const float* g1_att= (const float*)d_in[7];
  const float* g1_b  = (const float*)d_in[8];
  const float* g2_wl = (const float*)d_in[9];
  const float* g2_wr = (const float*)d_in[10];
  const float* g2_we = (const float*)d_in[11];
  const float* g2_att= (const float*)d_in[12];
  const float* g2_b  = (const float*)d_in[13];
  const float* wih_f = (const float*)d_in[14];
  const float* whh_f = (const float*)d_in[15];
  const float* bih_f = (const float*)d_in[16];
  const float* bhh_f = (const float*)d_in[17];
  const float* wih_b = (const float*)d_in[18];
  const float* whh_b = (const float*)d_in[19];
  const float* bih_b = (const float*)d_in[20];
  const float* bhh_b = (const float*)d_in[21];
  const float* fc_w  = (const float*)d_in[22];
  const float* fc_b  = (const float*)d_in[23];
  float* out = (float*)d_out;

  float* ws = (float*)d_ws;
  size_t o = 0;
  float* emb  = ws + o; o += (size_t)T_SEQ * N_NODES * HID;   // 20.48M
  float* xlr1 = ws + o; o += (size_t)N_NODES * 1024;          // 10.24M (also reused as xlr2)
  float* h1   = ws + o; o += (size_t)N_NODES * HC;            //  5.12M
  float* hA   = ws + o; o += (size_t)N_NODES * GRU_H;         //  2.56M (fwd final)
  float* hB   = ws + o; o += (size_t)N_NODES * GRU_H;         //  pong
  float* hC   = ws + o; o += (size_t)N_NODES * GRU_H;         //  bwd final
  float* lsum = ws + o; o += (size_t)N_NODES * 3;
  float* lattr= ws + o; o += (size_t)N_NODES * 3;
  float* gmean= ws + o; o += 512;
  unsigned short* W1h = (unsigned short*)(ws + o); o += 1024*128/2;
  unsigned short* W1l = (unsigned short*)(ws + o); o += 1024*128/2;
  unsigned short* W2h = (unsigned short*)(ws + o); o += 128*512/2;
  unsigned short* W2l = (unsigned short*)(ws + o); o += 128*512/2;
  unsigned short* Wgh_f = (unsigned short*)(ws + o); o += G3*320/2;
  unsigned short* Wgl_f = (unsigned short*)(ws + o); o += G3*320/2;
  unsigned short* Wgh_b = (unsigned short*)(ws + o); o += G3*320/2;
  unsigned short* Wgl_b = (unsigned short*)(ws + o); o += G3*320/2;
  int* deg     = (int*)(ws + o);
  int* row_ptr = deg + N_NODES;
  int* cursor  = row_ptr + N_NODES + 1;
  int* col     = cursor + N_NODES;
  float* xlr2 = xlr1;   // alias: xlr1 dead once GEMM2 runs

  hipMemsetAsync(deg,    0, N_NODES * sizeof(int), stream);
  hipMemsetAsync(cursor, 0, N_NODES * sizeof(int), stream);
  hipMemsetAsync(lsum,   0, (size_t)N_NODES * 3 * sizeof(float), stream);
  hipMemsetAsync(gmean,  0, 512 * sizeof(float), stream);
  hipMemsetAsync(hA,     0, (size_t)N_NODES * GRU_H * sizeof(float), stream);
  hipMemsetAsync(hC,     0, (size_t)N_NODES * GRU_H * sizeof(float), stream);

  deg_loop_kernel<<<(E_EDGES + 255)/256, 256, 0, stream>>>(edst, eattr, deg, lsum);
  loop_div_kernel<<<(N_NODES + 255)/256, 256, 0, stream>>>(deg, lsum, lattr);
  scan_rowptr_kernel<<<1, 256, 0, stream>>>(deg, row_ptr);
  csr_fill_kernel<<<(EF + 255)/256, 256, 0, stream>>>(edst, row_ptr, cursor, col);
  split_w_gat1<<<(1024*128 + 255)/256, 256, 0, stream>>>(g1_wl, g1_wr, W1h, W1l);
  split_w_gat2<<<(128*512 + 255)/256, 256, 0, stream>>>(g2_wl, g2_wr, W2h, W2l);
  split_w_gru<<<(G3*320 + 255)/256, 256, 0, stream>>>(wih_f, whh_f, Wgh_f, Wgl_f);
  split_w_gru<<<(G3*320 + 255)/256, 256, 0, stream>>>(wih_b, whh_b, Wgh_b, Wgl_b);

  const int MB = (N_NODES + 63) / 64;    // 157
  for (int t = 0; t < T_SEQ; t++){
    const float* xt = x + (size_t)t * N_NODES * IN_CH;
    mgemm<<<dim3(MB, 16), 256, 0, stream>>>(xt, W1h, W1l, xlr1, N_NODES, IN_CH, 1024);
    gat1_fused<<<(N_NODES*HEADS + 3)/4, 256, 0, stream>>>(
        xlr1, eattr, lattr, esrc, row_ptr, col, g1_we, g1_att, g1_b, h1);
    mgemm<<<dim3(MB, 2), 256, 0, stream>>>(h1, W2h, W2l, xlr2, N_NODES, HC, 128);
    gat2_fused<<<(N_NODES + 3)/4, 256, 0, stream>>>(
        xlr2, eattr, lattr, esrc, row_ptr, col, g2_we, g2_att, g2_b,
        emb + (size_t)t * N_NODES * HID);
  }

  // forward GRU: ping-pong hA <-> hB, final lands in hA (32 steps)
  {
    float* hin = hA; float* hout = hB;
    for (int s = 0; s < T_SEQ; s++){
      const float* Et = emb + (size_t)s * N_NODES * HID;
      gru_step<<<dim3(MB, 4), 256, 0, stream>>>(Et, hin, Wgh_f, Wgl_f, bih_f, bhh_f, hout);
      float* tmp = hin; hin = hout; hout = tmp;
    }
    // final is in hin == hA
  }
  // backward GRU: hC <-> hB, final lands in hC
  {
    float* hin = hC; float* hout = hB;
    for (int s = 0; s < T_SEQ; s++){
      int t = T_SEQ - 1 - s;
      const float* Et = emb + (size_t)t * N_NODES * HID;
      gru_step<<<dim3(MB, 4), 256, 0, stream>>>(Et, hin, Wgh_b, Wgl_b, bih_b, bhh_b, hout);
      float* tmp = hin; hin = hout; hout = tmp;
    }
  }

  mean_kernel<<<(N_NODES + 49)/50, 256, 0, stream>>>(hA, hC, gmean);
  fc_kernel<<<33, 64, 0, stream>>>(gmean, fc_w, fc_b, out);
}

// Round 3
// 8256.226 us; speedup vs baseline: 2.9584x; 1.4423x over previous
//
#include <hip/hip_runtime.h>

#define T_SEQ   32
#define N_NODES 10000
#define E_EDGES 160000
#define EF      (E_EDGES + N_NODES)
#define IN_CH   128
#define HID     64
#define HEADS   8
#define HC      512
#define GRU_H   256
#define G3      768

typedef __attribute__((ext_vector_type(8))) short short8;
typedef __attribute__((ext_vector_type(4))) float f32x4;

__device__ __forceinline__ float wave_reduce_sum(float v){
#pragma unroll
  for (int off = 32; off; off >>= 1) v += __shfl_xor(v, off, 64);
  return v;
}

__device__ __forceinline__ unsigned short f2bf(float v){
  unsigned u = __float_as_uint(v);
  unsigned r = u + 0x7FFFu + ((u >> 16) & 1u);
  return (unsigned short)(r >> 16);
}
__device__ __forceinline__ float bf2f(unsigned short b){
  return __uint_as_float(((unsigned)b) << 16);
}

// ---------------- graph setup ----------------

__global__ __launch_bounds__(256)
void deg_loop_kernel(const int* __restrict__ edst, const float* __restrict__ eattr,
                     int* __restrict__ deg, float* __restrict__ lsum){
  int e = blockIdx.x * 256 + threadIdx.x;
  if (e < E_EDGES){
    int d = edst[e];
    atomicAdd(&deg[d], 1);
    atomicAdd(&lsum[d*3+0], eattr[e*3+0]);
    atomicAdd(&lsum[d*3+1], eattr[e*3+1]);
    atomicAdd(&lsum[d*3+2], eattr[e*3+2]);
  }
}

__global__ __launch_bounds__(256)
void loop_div_kernel(const int* __restrict__ deg, const float* __restrict__ lsum,
                     float* __restrict__ lattr){
  int n = blockIdx.x * 256 + threadIdx.x;
  if (n < N_NODES){
    float d = fmaxf((float)deg[n], 1.0f);
    lattr[n*3+0] = lsum[n*3+0] / d;
    lattr[n*3+1] = lsum[n*3+1] / d;
    lattr[n*3+2] = lsum[n*3+2] / d;
  }
}

// row_ptr over REAL edges only (self loops handled explicitly in GAT kernels)
__global__ __launch_bounds__(256)
void scan_rowptr_kernel(const int* __restrict__ deg, int* __restrict__ row_ptr){
  __shared__ int sums[256];
  __shared__ int base[256];
  int tid = threadIdx.x;
  const int CH = 40;
  int start = tid * CH;
  int s = 0;
  for (int k = 0; k < CH; k++){
    int n = start + k;
    if (n < N_NODES) s += deg[n];
  }
  sums[tid] = s;
  __syncthreads();
  if (tid == 0){
    int acc = 0;
    for (int i = 0; i < 256; i++){ base[i] = acc; acc += sums[i]; }
  }
  __syncthreads();
  int acc = base[tid];
  for (int k = 0; k < CH; k++){
    int n = start + k;
    if (n < N_NODES){ row_ptr[n] = acc; acc += deg[n]; }
    else if (n == N_NODES){ row_ptr[n] = acc; }
  }
}

__global__ __launch_bounds__(256)
void csr_fill_kernel(const int* __restrict__ edst, const int* __restrict__ row_ptr,
                     int* __restrict__ cursor, int* __restrict__ col){
  int e = blockIdx.x * 256 + threadIdx.x;
  if (e < E_EDGES){
    int d = edst[e];
    int pos = row_ptr[d] + atomicAdd(&cursor[d], 1);
    col[pos] = e;
  }
}

// packed per-edge meta: {a0, a1, a2, src_as_float}; entries E_EDGES..EF-1 = self loops
__global__ __launch_bounds__(256)
void build_emeta(const float* __restrict__ eattr, const float* __restrict__ lattr,
                 const int* __restrict__ esrc, float4* __restrict__ emeta){
  int e = blockIdx.x * 256 + threadIdx.x;
  if (e < E_EDGES){
    emeta[e] = make_float4(eattr[e*3], eattr[e*3+1], eattr[e*3+2], __int_as_float(esrc[e]));
  } else if (e < EF){
    int n = e - E_EDGES;
    emeta[e] = make_float4(lattr[n*3], lattr[n*3+1], lattr[n*3+2], __int_as_float(n));
  }
}

// ---------------- weight prep: transpose + hi/lo bf16 split ----------------

__global__ __launch_bounds__(256)
void split_w_gat1(const float* __restrict__ wl, const float* __restrict__ wr,
                  unsigned short* __restrict__ hi, unsigned short* __restrict__ lo){
  int idx = blockIdx.x * 256 + threadIdx.x;
  if (idx >= 1024 * 128) return;
  int n = idx >> 7, k = idx & 127;
  float v = (n < 512) ? wl[k * 512 + n] : wr[k * 512 + (n - 512)];
  unsigned short h = f2bf(v);
  hi[idx] = h; lo[idx] = f2bf(v - bf2f(h));
}

__global__ __launch_bounds__(256)
void split_w_gat2(const float* __restrict__ wl, const float* __restrict__ wr,
                  unsigned short* __restrict__ hi, unsigned short* __restrict__ lo){
  int idx = blockIdx.x * 256 + threadIdx.x;
  if (idx >= 128 * 512) return;
  int n = idx >> 9, k = idx & 511;
  float v = (n < 64) ? wl[k * 64 + n] : wr[k * 64 + (n - 64)];
  unsigned short h = f2bf(v);
  hi[idx] = h; lo[idx] = f2bf(v - bf2f(h));
}

__global__ __launch_bounds__(256)
void split_w_gru(const float* __restrict__ wih, const float* __restrict__ whh,
                 unsigned short* __restrict__ hi, unsigned short* __restrict__ lo){
  int idx = blockIdx.x * 256 + threadIdx.x;
  if (idx >= G3 * 320) return;
  int n = idx / 320, k = idx - n * 320;
  float v = (k < 64) ? wih[n * 64 + k] : whh[n * 256 + (k - 64)];
  unsigned short h = f2bf(v);
  hi[idx] = h; lo[idx] = f2bf(v - bf2f(h));
}

// ---------------- bf16x3 MFMA GEMM ----------------
#define LDK 40

__global__ __launch_bounds__(256)
void mgemm(const float* __restrict__ A, const unsigned short* __restrict__ Bh,
           const unsigned short* __restrict__ Bl, float* __restrict__ C,
           int M, int K, int N){
  __shared__ __align__(16) short As_h[64 * LDK];
  __shared__ __align__(16) short As_l[64 * LDK];
  __shared__ __align__(16) short Bs_h[64 * LDK];
  __shared__ __align__(16) short Bs_l[64 * LDK];
  int tid = threadIdx.x;
  int m0 = blockIdx.x * 64, n0 = blockIdx.y * 64;
  int w = tid >> 6, lane = tid & 63;
  int wm = w >> 1, wn = w & 1;
  int m16 = lane & 15, quad = lane >> 4;

  f32x4 acc[2][2];
#pragma unroll
  for (int i = 0; i < 2; i++)
#pragma unroll
    for (int j = 0; j < 2; j++) acc[i][j] = (f32x4){0.f,0.f,0.f,0.f};

  int ar = tid >> 2;
  int ak = (tid & 3) * 8;
  bool aval = (m0 + ar) < M;
  const float* Ap = A + (size_t)(m0 + ar) * K + ak;
  int bn = tid >> 2;
  int bk = (tid & 3) * 8;
  const unsigned short* Bhp = Bh + (size_t)(n0 + bn) * K + bk;
  const unsigned short* Blp = Bl + (size_t)(n0 + bn) * K + bk;

  for (int k0 = 0; k0 < K; k0 += 32){
#pragma unroll
    for (int c = 0; c < 2; c++){
      float4 v = aval ? *(const float4*)(Ap + k0 + c * 4) : make_float4(0,0,0,0);
      unsigned short h0=f2bf(v.x), h1=f2bf(v.y), h2=f2bf(v.z), h3=f2bf(v.w);
      unsigned short l0=f2bf(v.x-bf2f(h0)), l1=f2bf(v.y-bf2f(h1)),
                     l2=f2bf(v.z-bf2f(h2)), l3=f2bf(v.w-bf2f(h3));
      *(ushort4*)&As_h[ar*LDK + ak + c*4] = make_ushort4(h0,h1,h2,h3);
      *(ushort4*)&As_l[ar*LDK + ak + c*4] = make_ushort4(l0,l1,l2,l3);
    }
    *(float4*)&Bs_h[bn*LDK + bk] = *(const float4*)(Bhp + k0);
    *(float4*)&Bs_l[bn*LDK + bk] = *(const float4*)(Blp + k0);
    __syncthreads();

    short8 a_h[2], a_l[2], b_h[2], b_l[2];
#pragma unroll
    for (int mt = 0; mt < 2; mt++){
      int r = wm*32 + mt*16 + m16;
      a_h[mt] = *(const short8*)&As_h[r*LDK + quad*8];
      a_l[mt] = *(const short8*)&As_l[r*LDK + quad*8];
    }
#pragma unroll
    for (int nt = 0; nt < 2; nt++){
      int r = wn*32 + nt*16 + m16;
      b_h[nt] = *(const short8*)&Bs_h[r*LDK + quad*8];
      b_l[nt] = *(const short8*)&Bs_l[r*LDK + quad*8];
    }
#pragma unroll
    for (int mt = 0; mt < 2; mt++)
#pragma unroll
      for (int nt = 0; nt < 2; nt++){
        acc[mt][nt] = __builtin_amdgcn_mfma_f32_16x16x32_bf16(a_h[mt], b_h[nt], acc[mt][nt], 0,0,0);
        acc[mt][nt] = __builtin_amdgcn_mfma_f32_16x16x32_bf16(a_h[mt], b_l[nt], acc[mt][nt], 0,0,0);
        acc[mt][nt] = __builtin_amdgcn_mfma_f32_16x16x32_bf16(a_l[mt], b_h[nt], acc[mt][nt], 0,0,0);
      }
    __syncthreads();
  }
#pragma unroll
  for (int mt = 0; mt < 2; mt++){
    int row = m0 + wm*32 + mt*16 + quad*4;
#pragma unroll
    for (int nt = 0; nt < 2; nt++){
      int cc = n0 + wn*32 + nt*16 + m16;
#pragma unroll
      for (int r4 = 0; r4 < 4; r4++){
        if (row + r4 < M) C[(size_t)(row + r4) * N + cc] = acc[mt][nt][r4];
      }
    }
  }
}

// ---------------- fused GRU step ----------------
__global__ __launch_bounds__(256)
void gru_step(const float* __restrict__ Et, const float* __restrict__ Hin,
              const unsigned short* __restrict__ Wh, const unsigned short* __restrict__ Wl,
              const float* __restrict__ bih, const float* __restrict__ bhh,
              float* __restrict__ Hout){
  __shared__ __align__(16) short As_h[64 * LDK];
  __shared__ __align__(16) short As_l[64 * LDK];
  __shared__ __align__(16) short Bs_h[3 * 64 * LDK];
  __shared__ __align__(16) short Bs_l[3 * 64 * LDK];
  int tid = threadIdx.x;
  int m0 = blockIdx.x * 64;
  int j0 = blockIdx.y * 64;
  int w = tid >> 6, lane = tid & 63;
  int wm = w >> 1, wn = w & 1;
  int m16 = lane & 15, quad = lane >> 4;

  f32x4 acc_r[2][2], acc_z[2][2], acc_ni[2][2], acc_nh[2][2];
#pragma unroll
  for (int i = 0; i < 2; i++)
#pragma unroll
    for (int j = 0; j < 2; j++){
      acc_r[i][j] = (f32x4){0,0,0,0}; acc_z[i][j] = (f32x4){0,0,0,0};
      acc_ni[i][j] = (f32x4){0,0,0,0}; acc_nh[i][j] = (f32x4){0,0,0,0};
    }

  int ar = tid >> 2;
  int ak = (tid & 3) * 8;
  bool aval = (m0 + ar) < N_NODES;
  int bn = tid >> 2;
  int bk = (tid & 3) * 8;

  for (int k0 = 0; k0 < 320; k0 += 32){
    const float* src; int stride, koff;
    if (k0 < 64){ src = Et; stride = 64; koff = k0; }
    else        { src = Hin; stride = GRU_H; koff = k0 - 64; }
#pragma unroll
    for (int c = 0; c < 2; c++){
      float4 v = aval ? *(const float4*)(src + (size_t)(m0 + ar) * stride + koff + ak + c * 4)
                      : make_float4(0,0,0,0);
      unsigned short h0=f2bf(v.x), h1=f2bf(v.y), h2=f2bf(v.z), h3=f2bf(v.w);
      unsigned short l0=f2bf(v.x-bf2f(h0)), l1=f2bf(v.y-bf2f(h1)),
                     l2=f2bf(v.z-bf2f(h2)), l3=f2bf(v.w-bf2f(h3));
      *(ushort4*)&As_h[ar*LDK + ak + c*4] = make_ushort4(h0,h1,h2,h3);
      *(ushort4*)&As_l[ar*LDK + ak + c*4] = make_ushort4(l0,l1,l2,l3);
    }
#pragma unroll
    for (int g = 0; g < 3; g++){
      size_t wrow = (size_t)(g * GRU_H + j0 + bn) * 320 + k0 + bk;
      *(float4*)&Bs_h[(g*64 + bn)*LDK + bk] = *(const float4*)(Wh + wrow);
      *(float4*)&Bs_l[(g*64 + bn)*LDK + bk] = *(const float4*)(Wl + wrow);
    }
    __syncthreads();

    short8 a_h[2], a_l[2];
#pragma unroll
    for (int mt = 0; mt < 2; mt++){
      int r = wm*32 + mt*16 + m16;
      a_h[mt] = *(const short8*)&As_h[r*LDK + quad*8];
      a_l[mt] = *(const short8*)&As_l[r*LDK + quad*8];
    }
#pragma unroll
    for (int g = 0; g < 3; g++){
      short8 b_h[2], b_l[2];
#pragma unroll
      for (int nt = 0; nt < 2; nt++){
        int r = g*64 + wn*32 + nt*16 + m16;
        b_h[nt] = *(const short8*)&Bs_h[r*LDK + quad*8];
        b_l[nt] = *(const short8*)&Bs_l[r*LDK + quad*8];
      }
      f32x4* accp = (g == 0) ? &acc_r[0][0] : (g == 1) ? &acc_z[0][0]
                   : (k0 < 64) ? &acc_ni[0][0] : &acc_nh[0][0];
#pragma unroll
      for (int mt = 0; mt < 2; mt++)
#pragma unroll
        for (int nt = 0; nt < 2; nt++){
          f32x4 a = accp[mt*2+nt];
          a = __builtin_amdgcn_mfma_f32_16x16x32_bf16(a_h[mt], b_h[nt], a,0,0,0);
          a = __builtin_amdgcn_mfma_f32_16x16x32_bf16(a_h[mt], b_l[nt], a,0,0,0);
          a = __builtin_amdgcn_mfma_f32_16x16x32_bf16(a_l[mt], b_h[nt], a,0,0,0);
          accp[mt*2+nt] = a;
        }
    }
    __syncthreads();
  }

#pragma unroll
  for (int mt = 0; mt < 2; mt++){
    int row = m0 + wm*32 + mt*16 + quad*4;
#pragma unroll
    for (int nt = 0; nt < 2; nt++){
      int j = j0 + wn*32 + nt*16 + m16;
      float br = bih[j] + bhh[j];
      float bz = bih[GRU_H + j] + bhh[GRU_H + j];
      float bni = bih[2*GRU_H + j];
      float bnh = bhh[2*GRU_H + j];
#pragma unroll
      for (int r4 = 0; r4 < 4; r4++){
        int node = row + r4;
        if (node < N_NODES){
          float r = 1.f / (1.f + __expf(-(acc_r[mt][nt][r4] + br)));
          float z = 1.f / (1.f + __expf(-(acc_z[mt][nt][r4] + bz)));
          float nn = tanhf(acc_ni[mt][nt][r4] + bni + r * (acc_nh[mt][nt][r4] + bnh));
          float hold = Hin[(size_t)node * GRU_H + j];
          Hout[(size_t)node * GRU_H + j] = (1.f - z) * nn + z * hold;
        }
      }
    }
  }
}

// ---------------- fused GAT layer 1: wave per node, 8 heads, float4 lanes --

__global__ __launch_bounds__(256)
void gat1_fused(const float* __restrict__ xlr, const float4* __restrict__ emeta,
                const int* __restrict__ row_ptr, const int* __restrict__ col,
                const float* __restrict__ we, const float* __restrict__ att,
                const float* __restrict__ bias, float* __restrict__ out){
  int n = (blockIdx.x * 256 + threadIdx.x) >> 6;
  int lane = threadIdx.x & 63;
  if (n >= N_NODES) return;
  int ch0 = lane * 4;          // channels [0,256): heads 0..3, head = lane>>4
  int ch1 = 256 + lane * 4;    // channels [256,512): heads 4..7

  float4 att0 = *(const float4*)&att[ch0];
  float4 att1 = *(const float4*)&att[ch1];
  float4 we00 = *(const float4*)&we[ch0],        we01 = *(const float4*)&we[ch1];
  float4 we10 = *(const float4*)&we[512 + ch0],  we11 = *(const float4*)&we[512 + ch1];
  float4 we20 = *(const float4*)&we[1024 + ch0], we21 = *(const float4*)&we[1024 + ch1];
  const float* xrow_n = xlr + (size_t)n * 1024;
  float4 xr0 = *(const float4*)&xrow_n[512 + ch0];
  float4 xr1 = *(const float4*)&xrow_n[512 + ch1];

  float den0 = 0.f, den1 = 0.f;
  float4 acc0 = make_float4(0,0,0,0), acc1 = make_float4(0,0,0,0);
  int beg = row_ptr[n], end = row_ptr[n + 1];

  for (int p = beg - 1; p < end; p++){
    float4 mt = (p < beg) ? emeta[E_EDGES + n] : emeta[col[p]];
    float a0 = mt.x, a1 = mt.y, a2 = mt.z;
    int s = __float_as_int(mt.w);
    const float* xrow = xlr + (size_t)s * 1024;
    float4 xl0 = *(const float4*)&xrow[ch0];
    float4 xl1 = *(const float4*)&xrow[ch1];

    // half 0
    {
      float vx = xl0.x + xr0.x + a0*we00.x + a1*we10.x + a2*we20.x;
      float vy = xl0.y + xr0.y + a0*we00.y + a1*we10.y + a2*we20.y;
      float vz = xl0.z + xr0.z + a0*we00.z + a1*we10.z + a2*we20.z;
      float vw = xl0.w + xr0.w + a0*we00.w + a1*we10.w + a2*we20.w;
      vx = fmaxf(vx, 0.2f*vx); vy = fmaxf(vy, 0.2f*vy);
      vz = fmaxf(vz, 0.2f*vz); vw = fmaxf(vw, 0.2f*vw);
      float pm = vx*att0.x + vy*att0.y + vz*att0.z + vw*att0.w;
      pm += __shfl_xor(pm, 1, 64); pm += __shfl_xor(pm, 2, 64);
      pm += __shfl_xor(pm, 4, 64); pm += __shfl_xor(pm, 8, 64);
      float wgt = __expf(pm);
      den0 += wgt;
      acc0.x += wgt * xl0.x; acc0.y += wgt * xl0.y;
      acc0.z += wgt * xl0.z; acc0.w += wgt * xl0.w;
    }
    // half 1
    {
      float vx = xl1.x + xr1.x + a0*we01.x + a1*we11.x + a2*we21.x;
      float vy = xl1.y + xr1.y + a0*we01.y + a1*we11.y + a2*we21.y;
      float vz = xl1.z + xr1.z + a0*we01.z + a1*we11.z + a2*we21.z;
      float vw = xl1.w + xr1.w + a0*we01.w + a1*we11.w + a2*we21.w;
      vx = fmaxf(vx, 0.2f*vx); vy = fmaxf(vy, 0.2f*vy);
      vz = fmaxf(vz, 0.2f*vz); vw = fmaxf(vw, 0.2f*vw);
      float pm = vx*att1.x + vy*att1.y + vz*att1.z + vw*att1.w;
      pm += __shfl_xor(pm, 1, 64); pm += __shfl_xor(pm, 2, 64);
      pm += __shfl_xor(pm, 4, 64); pm += __shfl_xor(pm, 8, 64);
      float wgt = __expf(pm);
      den1 += wgt;
      acc1.x += wgt * xl1.x; acc1.y += wgt * xl1.y;
      acc1.z += wgt * xl1.z; acc1.w += wgt * xl1.w;
    }
  }

  float4 b0 = *(const float4*)&bias[ch0];
  float4 b1 = *(const float4*)&bias[ch1];
  float4 o0, o1;
  float id0 = 1.f / den0, id1 = 1.f / den1;
  o0.x = acc0.x*id0 + b0.x; o0.y = acc0.y*id0 + b0.y;
  o0.z = acc0.z*id0 + b0.z; o0.w = acc0.w*id0 + b0.w;
  o1.x = acc1.x*id1 + b1.x; o1.y = acc1.y*id1 + b1.y;
  o1.z = acc1.z*id1 + b1.z; o1.w = acc1.w*id1 + b1.w;
  o0.x = o0.x > 0.f ? o0.x : (__expf(o0.x)-1.f);
  o0.y = o0.y > 0.f ? o0.y : (__expf(o0.y)-1.f);
  o0.z = o0.z > 0.f ? o0.z : (__expf(o0.z)-1.f);
  o0.w = o0.w > 0.f ? o0.w : (__expf(o0.w)-1.f);
  o1.x = o1.x > 0.f ? o1.x : (__expf(o1.x)-1.f);
  o1.y = o1.y > 0.f ? o1.y : (__expf(o1.y)-1.f);
  o1.z = o1.z > 0.f ? o1.z : (__expf(o1.z)-1.f);
  o1.w = o1.w > 0.f ? o1.w : (__expf(o1.w)-1.f);
  *(float4*)&out[(size_t)n * 512 + ch0] = o0;
  *(float4*)&out[(size_t)n * 512 + ch1] = o1;
}

// ---------------- fused GAT layer 2: wave per node, 4 edges in flight ------

__global__ __launch_bounds__(256)
void gat2_fused(const float* __restrict__ xlr, const float4* __restrict__ emeta,
                const int* __restrict__ row_ptr, const int* __restrict__ col,
                const float* __restrict__ we, const float* __restrict__ att,
                const float* __restrict__ bias, float* __restrict__ out){
  int n = (blockIdx.x * 256 + threadIdx.x) >> 6;
  int lane = threadIdx.x & 63;
  if (n >= N_NODES) return;
  int g = lane >> 4;        // edge slot 0..3
  int c4 = (lane & 15) * 4; // channel group

  float4 attq = *(const float4*)&att[c4];
  float4 we0q = *(const float4*)&we[c4];
  float4 we1q = *(const float4*)&we[64 + c4];
  float4 we2q = *(const float4*)&we[128 + c4];
  float4 xr4  = *(const float4*)&xlr[(size_t)n * 128 + 64 + c4];

  float den = 0.f;
  float4 acc = make_float4(0,0,0,0);
  int beg = row_ptr[n], end = row_ptr[n + 1];

  for (int p0 = beg - 1; p0 < end; p0 += 4){
    int pp = p0 + g;
    bool valid = pp < end;
    int s = n; float a0 = 0.f, a1 = 0.f, a2 = 0.f;
    if (valid){
      float4 mt = (pp < beg) ? emeta[E_EDGES + n] : emeta[col[pp]];
      a0 = mt.x; a1 = mt.y; a2 = mt.z; s = __float_as_int(mt.w);
    }
    float4 xl4 = *(const float4*)&xlr[(size_t)s * 128 + c4];
    float vx = xl4.x + xr4.x + a0*we0q.x + a1*we1q.x + a2*we2q.x;
    float vy = xl4.y + xr4.y + a0*we0q.y + a1*we1q.y + a2*we2q.y;
    float vz = xl4.z + xr4.z + a0*we0q.z + a1*we1q.z + a2*we2q.z;
    float vw = xl4.w + xr4.w + a0*we0q.w + a1*we1q.w + a2*we2q.w;
    vx = fmaxf(vx, 0.2f*vx); vy = fmaxf(vy, 0.2f*vy);
    vz = fmaxf(vz, 0.2f*vz); vw = fmaxf(vw, 0.2f*vw);
    float pm = vx*attq.x + vy*attq.y + vz*attq.z + vw*attq.w;
    pm += __shfl_xor(pm, 1, 64); pm += __shfl_xor(pm, 2, 64);
    pm += __shfl_xor(pm, 4, 64); pm += __shfl_xor(pm, 8, 64);
    float wgt = valid ? __expf(pm) : 0.f;
    den += wgt;
    acc.x += wgt * xl4.x; acc.y += wgt * xl4.y;
    acc.z += wgt * xl4.z; acc.w += wgt * xl4.w;
  }
  // combine the 4 edge groups
#pragma unroll
  for (int off = 16; off <= 32; off <<= 1){
    den   += __shfl_xor(den, off, 64);
    acc.x += __shfl_xor(acc.x, off, 64);
    acc.y += __shfl_xor(acc.y, off, 64);
    acc.z += __shfl_xor(acc.z, off, 64);
    acc.w += __shfl_xor(acc.w, off, 64);
  }
  if (g == 0){
    float4 bq = *(const float4*)&bias[c4];
    float id = 1.f / den;
    float4 o;
    o.x = acc.x*id + bq.x; o.y = acc.y*id + bq.y;
    o.z = acc.z*id + bq.z; o.w = acc.w*id + bq.w;
    o.x = o.x > 0.f ? o.x : (__expf(o.x)-1.f);
    o.y = o.y > 0.f ? o.y : (__expf(o.y)-1.f);
    o.z = o.z > 0.f ? o.z : (__expf(o.z)-1.f);
    o.w = o.w > 0.f ? o.w : (__expf(o.w)-1.f);
    *(float4*)&out[(size_t)n * 64 + c4] = o;
  }
}

// ---------------- tail ----------------

__global__ __launch_bounds__(256)
void mean_kernel(const float* __restrict__ hf, const float* __restrict__ hb,
                 float* __restrict__ g){
  int k = threadIdx.x;
  int n0 = blockIdx.x * 50;
  int n1 = n0 + 50; if (n1 > N_NODES) n1 = N_NODES;
  float sf = 0.f, sb = 0.f;
  for (int n = n0; n < n1; n++){
    sf += hf[(size_t)n * GRU_H + k];
    sb += hb[(size_t)n * GRU_H + k];
  }
  atomicAdd(&g[k], sf);
  atomicAdd(&g[GRU_H + k], sb);
}

__global__ __launch_bounds__(64)
void fc_kernel(const float* __restrict__ g, const float* __restrict__ W,
               const float* __restrict__ b, float* __restrict__ out){
  int j = blockIdx.x;
  int lane = threadIdx.x;
  float s = 0.f;
  for (int k = lane; k < 2 * GRU_H; k += 64) s += g[k] * W[j * (2 * GRU_H) + k];
  s = wave_reduce_sum(s);
  if (lane == 0) out[j] = b[j] + s * (1.0f / N_NODES);
}

// ---------------- launch ----------------

extern "C" void kernel_launch(void* const* d_in, const int* in_sizes, int n_in,
                              void* d_out, int out_size, void* d_ws, size_t ws_size,
                              hipStream_t stream){
  const float* x     = (const float*)d_in[0];
  const float* eattr = (const float*)d_in[1];
  const int*   esrc  = (const int*)  d_in[2];
  const int*   edst  = (const int*)  d_in[3];
  const float* g1_wl = (const float*)d_in[4];
  const float* g1_wr = (const float*)d_in[5];
  const float* g1_we = (const float*)d_in[6];
  const float* g1_att= (const float*)d_in[7];
  const float* g1_b  = (const float*)d_in[8];
  const float* g2_wl = (const float*)d_in[9];
  const float* g2_wr = (const float*)d_in[10];
  const float* g2_we = (const float*)d_in[11];
  const float* g2_att= (const float*)d_in[12];
  const float* g2_b  = (const float*)d_in[13];
  const float* wih_f = (const float*)d_in[14];
  const float* whh_f = (const float*)d_in[15];
  const float* bih_f = (const float*)d_in[16];
  const float* bhh_f = (const float*)d_in[17];
  const float* wih_b = (const float*)d_in[18];
  const float* whh_b = (const float*)d_in[19];
  const float* bih_b = (const float*)d_in[20];
  const float* bhh_b = (const float*)d_in[21];
  const float* fc_w  = (const float*)d_in[22];
  const float* fc_b  = (const float*)d_in[23];
  float* out = (float*)d_out;

  float* ws = (float*)d_ws;
  size_t o = 0;
  float* emb  = ws + o; o += (size_t)T_SEQ * N_NODES * HID;
  float* xlr1 = ws + o; o += (size_t)N_NODES * 1024;
  float* h1   = ws + o; o += (size_t)N_NODES * HC;
  float* hA   = ws + o; o += (size_t)N_NODES * GRU_H;
  float* hB   = ws + o; o += (size_t)N_NODES * GRU_H;
  float* hC   = ws + o; o += (size_t)N_NODES * GRU_H;
  float* lsum = ws + o; o += (size_t)N_NODES * 3;
  float* lattr= ws + o; o += (size_t)N_NODES * 3;
  float* gmean= ws + o; o += 512;
  o = (o + 3) & ~(size_t)3;                       // align for float4
  float4* emeta = (float4*)(ws + o); o += (size_t)EF * 4;
  unsigned short* W1h = (unsigned short*)(ws + o); o += 1024*128/2;
  unsigned short* W1l = (unsigned short*)(ws + o); o += 1024*128/2;
  unsigned short* W2h = (unsigned short*)(ws + o); o += 128*512/2;
  unsigned short* W2l = (unsigned short*)(ws + o); o += 128*512/2;
  unsigned short* Wgh_f = (unsigned short*)(ws + o); o += G3*320/2;
  unsigned short* Wgl_f = (unsigned short*)(ws + o); o += G3*320/2;
  unsigned short* Wgh_b = (unsigned short*)(ws + o); o += G3*320/2;
  unsigned short* Wgl_b = (unsigned short*)(ws + o); o += G3*320/2;
  int* deg     = (int*)(ws + o);
  int* row_ptr = deg + N_NODES;
  int* cursor  = row_ptr + N_NODES + 1;
  int* col     = cursor + N_NODES;
  float* xlr2 = xlr1;

  hipMemsetAsync(deg,    0, N_NODES * sizeof(int), stream);
  hipMemsetAsync(cursor, 0, N_NODES * sizeof(int), stream);
  hipMemsetAsync(lsum,   0, (size_t)N_NODES * 3 * sizeof(float), stream);
  hipMemsetAsync(gmean,  0, 512 * sizeof(float), stream);
  hipMemsetAsync(hA,     0, (size_t)N_NODES * GRU_H * sizeof(float), stream);
  hipMemsetAsync(hC,     0, (size_t)N_NODES * GRU_H * sizeof(float), stream);

  deg_loop_kernel<<<(E_EDGES + 255)/256, 256, 0, stream>>>(edst, eattr, deg, lsum);
  loop_div_kernel<<<(N_NODES + 255)/256, 256, 0, stream>>>(deg, lsum, lattr);
  scan_rowptr_kernel<<<1, 256, 0, stream>>>(deg, row_ptr);
  csr_fill_kernel<<<(E_EDGES + 255)/256, 256, 0, stream>>>(edst, row_ptr, cursor, col);
  build_emeta<<<(EF + 255)/256, 256, 0, stream>>>(eattr, lattr, esrc, emeta);
  split_w_gat1<<<(1024*128 + 255)/256, 256, 0, stream>>>(g1_wl, g1_wr, W1h, W1l);
  split_w_gat2<<<(128*512 + 255)/256, 256, 0, stream>>>(g2_wl, g2_wr, W2h, W2l);
  split_w_gru<<<(G3*320 + 255)/256, 256, 0, stream>>>(wih_f, whh_f, Wgh_f, Wgl_f);
  split_w_gru<<<(G3*320 + 255)/256, 256, 0, stream>>>(wih_b, whh_b, Wgh_b, Wgl_b);

  const int MB = (N_NODES + 63) / 64;    // 157
  const int NODE_BLOCKS = (N_NODES + 3) / 4;  // 4 waves/block
  for (int t = 0; t < T_SEQ; t++){
    const float* xt = x + (size_t)t * N_NODES * IN_CH;
    mgemm<<<dim3(MB, 16), 256, 0, stream>>>(xt, W1h, W1l, xlr1, N_NODES, IN_CH, 1024);
    gat1_fused<<<NODE_BLOCKS, 256, 0, stream>>>(
        xlr1, emeta, row_ptr, col, g1_we, g1_att, g1_b, h1);
    mgemm<<<dim3(MB, 2), 256, 0, stream>>>(h1, W2h, W2l, xlr2, N_NODES, HC, 128);
    gat2_fused<<<NODE_BLOCKS, 256, 0, stream>>>(
        xlr2, emeta, row_ptr, col, g2_we, g2_att, g2_b,
        emb + (size_t)t * N_NODES * HID);
  }

  {
    float* hin = hA; float* hout = hB;
    for (int s = 0; s < T_SEQ; s++){
      const float* Et = emb + (size_t)s * N_NODES * HID;
      gru_step<<<dim3(MB, 4), 256, 0, stream>>>(Et, hin, Wgh_f, Wgl_f, bih_f, bhh_f, hout);
      float* tmp = hin; hin = hout; hout = tmp;
    }
  }
  {
    float* hin = hC; float* hout = hB;
    for (int s = 0; s < T_SEQ; s++){
      int t = T_SEQ - 1 - s;
      const float* Et = emb + (size_t)t * N_NODES * HID;
      gru_step<<<dim3(MB, 4), 256, 0, stream>>>(Et, hin, Wgh_b, Wgl_b, bih_b, bhh_b, hout);
      float* tmp = hin; hin = hout; hout = tmp;
    }
  }

  mean_kernel<<<(N_NODES + 49)/50, 256, 0, stream>>>(hA, hC, gmean);
  fc_kernel<<<33, 64, 0, stream>>>(gmean, fc_w, fc_b, out);
}